// Round 14
// baseline (2548.214 us; speedup 1.0000x reference)
//
#include <hip/hip_runtime.h>

typedef _Float16 half2v __attribute__((ext_vector_type(2)));
typedef _Float16 half8v __attribute__((ext_vector_type(8)));
typedef float f32x4 __attribute__((ext_vector_type(4)));
typedef int i32x8 __attribute__((ext_vector_type(8)));

#define S_LEN 2048

// barrier draining only LDS counters (cross-wave traffic is all LDS here)
#define LDS_BARRIER() asm volatile("s_waitcnt lgkmcnt(0)\n\ts_barrier" ::: "memory")

static __device__ __forceinline__ unsigned int pk16(float a, float b) {
  half2v h; h[0] = (_Float16)a; h[1] = (_Float16)b;
  return __builtin_bit_cast(unsigned int, h);
}
static __device__ __forceinline__ float uph(unsigned short u) {
  return (float)__builtin_bit_cast(_Float16, u);
}
static __device__ __forceinline__ unsigned short f16bits(float x) {
  return __builtin_bit_cast(unsigned short, (_Float16)x);
}
static __device__ __forceinline__ float rcp_f(float x) {
  return __builtin_amdgcn_rcpf(x);
}
static __device__ __forceinline__ float sigm(float x) {
  return rcp_f(1.0f + __expf(-x));
}
static __device__ __forceinline__ float tanh_fast(float x) {
  return 1.0f - 2.0f * rcp_f(__expf(2.0f * x) + 1.0f);   // safe at +/-inf
}
static __device__ __forceinline__ float sel4(f32x4 v, int b) {
  return (b == 0) ? v[0] : (b == 1) ? v[1] : (b == 2) ? v[2] : v[3];
}
static __device__ __forceinline__ unsigned char fp8b(float x) {
  return (unsigned char)(__builtin_amdgcn_cvt_pk_fp8_f32(x, x, 0, false) & 0xff);
}
// pack 32 consecutive f32 into 32 OCP-e4m3 bytes (one K=128 MFMA fragment)
static __device__ __forceinline__ i32x8 cvt32_fp8(const float* p) {
  i32x8 v;
  #pragma unroll
  for (int q = 0; q < 4; ++q) {
    int lo = 0, hi = 0;
    lo = __builtin_amdgcn_cvt_pk_fp8_f32(p[8*q+0], p[8*q+1], lo, false);
    lo = __builtin_amdgcn_cvt_pk_fp8_f32(p[8*q+2], p[8*q+3], lo, true);
    hi = __builtin_amdgcn_cvt_pk_fp8_f32(p[8*q+4], p[8*q+5], hi, false);
    hi = __builtin_amdgcn_cvt_pk_fp8_f32(p[8*q+6], p[8*q+7], hi, true);
    v[2*q] = lo; v[2*q+1] = hi;
  }
  return v;
}

// ---------------------------------------------------------------------------
// Kernel 1: P[m, g*256+j] = f16( x[m,:] . W{g}_x[j,:] + b{g}[j] )  (unchanged)
// ---------------------------------------------------------------------------
__global__ __launch_bounds__(256, 2) void gemm_pre(
    const float* __restrict__ x,
    const float* __restrict__ Wz, const float* __restrict__ bz,
    const float* __restrict__ Wr, const float* __restrict__ br,
    const float* __restrict__ Wc, const float* __restrict__ bc,
    const float* __restrict__ Wh, const float* __restrict__ bh,
    unsigned short* __restrict__ P)
{
  __shared__ __align__(16) char As[128 * 128];
  __shared__ __align__(16) char Bs[128 * 128];
  const int t = threadIdx.x;
  const int lane = t & 63;
  const int wid = t >> 6;
  const int wm = wid >> 1, wn = wid & 1;
  const int n0 = blockIdx.x * 128;
  const int m0 = blockIdx.y * 128;

  f32x4 acc[4][4];
  #pragma unroll
  for (int i = 0; i < 4; ++i)
    #pragma unroll
    for (int jq = 0; jq < 4; ++jq) acc[i][jq] = f32x4{0.f, 0.f, 0.f, 0.f};

  for (int kk = 0; kk < 4; ++kk) {
    __syncthreads();
    #pragma unroll
    for (int it = 0; it < 8; ++it) {
      int fl = it * 256 + t;
      int row = fl >> 4;
      int c4 = fl & 15;
      f32x4 v = *(const f32x4*)(x + (size_t)(m0 + row) * 256 + kk * 64 + c4 * 4);
      uint2 pw; pw.x = pk16(v[0], v[1]); pw.y = pk16(v[2], v[3]);
      *(uint2*)(As + row * 128 + ((c4 * 8) ^ ((row & 7) << 4))) = pw;

      int n = n0 + row;
      int g = n >> 8; int jc = n & 255;
      const float* W = (g == 0) ? Wz : (g == 1) ? Wr : (g == 2) ? Wc : Wh;
      f32x4 wv = *(const f32x4*)(W + jc * 512 + kk * 64 + c4 * 4);
      uint2 qw; qw.x = pk16(wv[0], wv[1]); qw.y = pk16(wv[2], wv[3]);
      *(uint2*)(Bs + row * 128 + ((c4 * 8) ^ ((row & 7) << 4))) = qw;
    }
    __syncthreads();
    #pragma unroll
    for (int k2 = 0; k2 < 2; ++k2) {
      const int kb = k2 * 64 + (lane >> 4) * 16;
      half8v a[4], bfr[4];
      #pragma unroll
      for (int i = 0; i < 4; ++i) {
        int ar = wm * 64 + i * 16 + (lane & 15);
        a[i] = *(const half8v*)(As + ar * 128 + (kb ^ ((ar & 7) << 4)));
        int br2 = wn * 64 + i * 16 + (lane & 15);
        bfr[i] = *(const half8v*)(Bs + br2 * 128 + (kb ^ ((br2 & 7) << 4)));
      }
      #pragma unroll
      for (int i = 0; i < 4; ++i)
        #pragma unroll
        for (int jq = 0; jq < 4; ++jq)
          acc[i][jq] = __builtin_amdgcn_mfma_f32_16x16x32_f16(a[i], bfr[jq], acc[i][jq], 0, 0, 0);
    }
  }
  #pragma unroll
  for (int jq = 0; jq < 4; ++jq) {
    int col = n0 + wn * 64 + jq * 16 + (lane & 15);
    int g = col >> 8; int jc = col & 255;
    const float* bp = (g == 0) ? bz : (g == 1) ? br : (g == 2) ? bc : bh;
    float bias = bp[jc];
    #pragma unroll
    for (int i = 0; i < 4; ++i) {
      int rowb = m0 + wm * 64 + i * 16 + (lane >> 4) * 4;
      #pragma unroll
      for (int r = 0; r < 4; ++r) {
        float vv = acc[i][jq][r] + bias;
        P[(size_t)(rowb + r) * 1024 + col] = f16bits(vv);
      }
    }
  }
}

// ---------------------------------------------------------------------------
// Kernel 2: sequential scan. 64 blocks x 512 threads (8 waves, 2/SIMD).
// Wave w owns rows [w*32,+32) of z, r, c as TWO MFMA groups sharing one
// B-fragment (halves CU DS traffic vs 16x1). All matvecs MX fp8 K=128
// (unit scales). r-MFMAs first (critical chain); z-gate deferred into
// phase C's MFMA shadow. h and rh published as fp8.
// ---------------------------------------------------------------------------
__global__ __launch_bounds__(512, 1) void gru_scan(
    const float* __restrict__ Wz, const float* __restrict__ Wr,
    const float* __restrict__ Wc,
    unsigned short* P, float* __restrict__ out)
{
  __shared__ __align__(16) unsigned char h8_lds[256];   // h as fp8 e4m3
  __shared__ __align__(16) unsigned char rh8_lds[256];  // r*h as fp8 e4m3

  const int t = threadIdx.x;
  const int b = blockIdx.x;
  const int w = t >> 6;            // 0..7
  const int l = t & 63;
  const int col = l & 15;
  const int khi = l >> 4;          // 0..3
  const int lb = l & 3;
  const bool owner = (col < 4);    // then lb == col
  const int j0 = w * 32 + khi * 4 + lb;
  const int j1 = j0 + 16;

  // ---- A-frags (K=128 scaled): lane (khi,col), group g, holds
  //      W[row=w*32+g*16+col][k = half*128 + khi*32 + e], e=0..31
  i32x8 wzMX[2][2], wrMX[2][2], wcMX[2][2];
  #pragma unroll
  for (int g = 0; g < 2; ++g) {
    int row = w * 32 + g * 16 + col;
    #pragma unroll
    for (int hf = 0; hf < 2; ++hf) {
      wzMX[g][hf] = cvt32_fp8(Wz + row * 512 + 256 + hf * 128 + khi * 32);
      wrMX[g][hf] = cvt32_fp8(Wr + row * 512 + 256 + hf * 128 + khi * 32);
      wcMX[g][hf] = cvt32_fp8(Wc + row * 512 + 256 + hf * 128 + khi * 32);
    }
  }

  if (t < 64) ((unsigned int*)h8_lds)[t] = 0u;

  float h0 = 0.f, h1 = 0.f;
  unsigned short czx0 = 0, czx1 = 0, crx0 = 0, crx1 = 0, ccx0 = 0, ccx1 = 0;
  if (owner) {
    const unsigned short* pb = P + b * 1024;
    czx0 = pb[j0]; czx1 = pb[j1];
    crx0 = pb[256 + j0]; crx1 = pb[256 + j1];
    ccx0 = pb[512 + j0]; ccx1 = pb[512 + j1];
  }
  int pcur = b * 1024;
  int pnext = pcur + 65536;
  __syncthreads();

  const f32x4 z4 = f32x4{0.f, 0.f, 0.f, 0.f};

  #pragma unroll 1
  for (int s = 0; s < S_LEN; ++s) {
    unsigned short nzx0 = 0, nzx1 = 0, nrx0 = 0, nrx1 = 0, ncx0 = 0, ncx1 = 0;
    if (owner && s + 1 < S_LEN) {
      nzx0 = P[pnext + j0];       nzx1 = P[pnext + j1];
      nrx0 = P[pnext + 256 + j0]; nrx1 = P[pnext + 256 + j1];
      ncx0 = P[pnext + 512 + j0]; ncx1 = P[pnext + 512 + j1];
    }
    // ---- Phase A: r (critical) then z matvecs; one shared B-frag pair
    i32x8 hB0 = *(const i32x8*)(h8_lds + khi * 32);
    i32x8 hB1 = *(const i32x8*)(h8_lds + 128 + khi * 32);
    f32x4 ar0 = z4, ar1 = z4, az0 = z4, az1 = z4;
    ar0 = __builtin_amdgcn_mfma_scale_f32_16x16x128_f8f6f4(
              wrMX[0][0], hB0, ar0, 0, 0, 0, 0x7F7F7F7F, 0, 0x7F7F7F7F);
    ar1 = __builtin_amdgcn_mfma_scale_f32_16x16x128_f8f6f4(
              wrMX[1][0], hB0, ar1, 0, 0, 0, 0x7F7F7F7F, 0, 0x7F7F7F7F);
    ar0 = __builtin_amdgcn_mfma_scale_f32_16x16x128_f8f6f4(
              wrMX[0][1], hB1, ar0, 0, 0, 0, 0x7F7F7F7F, 0, 0x7F7F7F7F);
    ar1 = __builtin_amdgcn_mfma_scale_f32_16x16x128_f8f6f4(
              wrMX[1][1], hB1, ar1, 0, 0, 0, 0x7F7F7F7F, 0, 0x7F7F7F7F);
    az0 = __builtin_amdgcn_mfma_scale_f32_16x16x128_f8f6f4(
              wzMX[0][0], hB0, az0, 0, 0, 0, 0x7F7F7F7F, 0, 0x7F7F7F7F);
    az1 = __builtin_amdgcn_mfma_scale_f32_16x16x128_f8f6f4(
              wzMX[1][0], hB0, az1, 0, 0, 0, 0x7F7F7F7F, 0, 0x7F7F7F7F);
    az0 = __builtin_amdgcn_mfma_scale_f32_16x16x128_f8f6f4(
              wzMX[0][1], hB1, az0, 0, 0, 0, 0x7F7F7F7F, 0, 0x7F7F7F7F);
    az1 = __builtin_amdgcn_mfma_scale_f32_16x16x128_f8f6f4(
              wzMX[1][1], hB1, az1, 0, 0, 0, 0x7F7F7F7F, 0, 0x7F7F7F7F);
    {
      float r0 = sigm(sel4(ar0, lb) + uph(crx0));
      float r1 = sigm(sel4(ar1, lb) + uph(crx1));
      if (owner) {
        rh8_lds[j0] = fp8b(r0 * h0);
        rh8_lds[j1] = fp8b(r1 * h1);
      }
    }
    LDS_BARRIER();                                     // (1) rh ready
    // ---- Phase C: c matvecs; z-gate/tanh math in the MFMA shadow
    i32x8 rB0 = *(const i32x8*)(rh8_lds + khi * 32);
    i32x8 rB1 = *(const i32x8*)(rh8_lds + 128 + khi * 32);
    f32x4 ac0 = z4, ac1 = z4;
    ac0 = __builtin_amdgcn_mfma_scale_f32_16x16x128_f8f6f4(
              wcMX[0][0], rB0, ac0, 0, 0, 0, 0x7F7F7F7F, 0, 0x7F7F7F7F);
    ac1 = __builtin_amdgcn_mfma_scale_f32_16x16x128_f8f6f4(
              wcMX[1][0], rB0, ac1, 0, 0, 0, 0x7F7F7F7F, 0, 0x7F7F7F7F);
    ac0 = __builtin_amdgcn_mfma_scale_f32_16x16x128_f8f6f4(
              wcMX[0][1], rB1, ac0, 0, 0, 0, 0x7F7F7F7F, 0, 0x7F7F7F7F);
    ac1 = __builtin_amdgcn_mfma_scale_f32_16x16x128_f8f6f4(
              wcMX[1][1], rB1, ac1, 0, 0, 0, 0x7F7F7F7F, 0, 0x7F7F7F7F);
    float zg0 = sigm(sel4(az0, lb) + uph(czx0));       // deferred z-gate
    float zg1 = sigm(sel4(az1, lb) + uph(czx1));
    float ht0 = tanh_fast(sel4(ac0, lb) + uph(ccx0));
    float ht1 = tanh_fast(sel4(ac1, lb) + uph(ccx1));
    float hn0 = (1.f - zg0) * h0 + zg0 * ht0;
    float hn1 = (1.f - zg1) * h1 + zg1 * ht1;
    h0 = hn0; h1 = hn1;
    if (owner) {
      h8_lds[j0] = fp8b(hn0);
      h8_lds[j1] = fp8b(hn1);
      P[pcur + j0] = f16bits(hn0);
      P[pcur + j1] = f16bits(hn1);
    }
    czx0 = nzx0; czx1 = nzx1; crx0 = nrx0; crx1 = nrx1; ccx0 = ncx0; ccx1 = ncx1;
    pcur += 65536; pnext += 65536;
    LDS_BARRIER();                                     // (2) h ready
  }
  if (owner) {
    out[(size_t)33554432 + b * 256 + j0] = h0;
    out[(size_t)33554432 + b * 256 + j1] = h1;
  }
}

// ---------------------------------------------------------------------------
// Kernel 3: g-gate + highway + LayerNorm as MFMA GEMM. (unchanged)
// ---------------------------------------------------------------------------
__global__ __launch_bounds__(512, 2) void g_mfma_ln(
    const float* __restrict__ Wh,
    const float* __restrict__ gamma, const float* __restrict__ beta,
    const unsigned short* __restrict__ P,
    float* __restrict__ out)
{
  __shared__ __align__(16) char As[128 * 128];    // hprev tile f16 (swizzled)
  __shared__ __align__(16) char Bs[256 * 128];    // Wg tile f16 (swizzled)
  __shared__ float red1[128][4];
  __shared__ float red2[128][4];
  __shared__ float2 murs[128];

  const int t = threadIdx.x;
  const int lane = t & 63;
  const int wid = t >> 6;
  const int wm = wid >> 2, wn = wid & 3;          // 2 x 4 wave grid
  const unsigned m0 = blockIdx.x * 128;

  float gam4[4], bet4[4];
  #pragma unroll
  for (int jq = 0; jq < 4; ++jq) {
    int col = wn * 64 + jq * 16 + (lane & 15);
    gam4[jq] = gamma[col];
    bet4[jq] = beta[col];
  }

  f32x4 acc[4][4];
  #pragma unroll
  for (int i = 0; i < 4; ++i)
    #pragma unroll
    for (int jq = 0; jq < 4; ++jq) acc[i][jq] = f32x4{0.f, 0.f, 0.f, 0.f};

  for (int kk = 0; kk < 4; ++kk) {
    __syncthreads();
    #pragma unroll
    for (int it = 0; it < 2; ++it) {
      int g = it * 512 + t;
      int row = g >> 3;
      int c8 = g & 7;
      int msrc = (int)m0 + row - 64;
      uint4 v = uint4{0u, 0u, 0u, 0u};
      if (msrc >= 0) v = *(const uint4*)(P + (unsigned)msrc * 1024 + kk * 64 + c8 * 8);
      *(uint4*)(As + row * 128 + ((c8 * 16) ^ ((row & 7) << 4))) = v;
    }
    #pragma unroll
    for (int it = 0; it < 4; ++it) {
      int g = it * 512 + t;
      int row = g >> 3;
      int c8 = g & 7;
      const float* src = Wh + row * 512 + 256 + kk * 64 + c8 * 8;
      f32x4 v0 = *(const f32x4*)(src);
      f32x4 v1 = *(const f32x4*)(src + 4);
      uint4 pw;
      pw.x = pk16(v0[0], v0[1]); pw.y = pk16(v0[2], v0[3]);
      pw.z = pk16(v1[0], v1[1]); pw.w = pk16(v1[2], v1[3]);
      *(uint4*)(Bs + row * 128 + ((c8 * 16) ^ ((row & 7) << 4))) = pw;
    }
    __syncthreads();
    #pragma unroll
    for (int k2 = 0; k2 < 2; ++k2) {
      const int kb = k2 * 64 + (lane >> 4) * 16;
      half8v a[4], bfr[4];
      #pragma unroll
      for (int i = 0; i < 4; ++i) {
        int ar = wm * 64 + i * 16 + (lane & 15);
        a[i] = *(const half8v*)(As + ar * 128 + (kb ^ ((ar & 7) << 4)));
        int br2 = wn * 64 + i * 16 + (lane & 15);
        bfr[i] = *(const half8v*)(Bs + br2 * 128 + (kb ^ ((br2 & 7) << 4)));
      }
      #pragma unroll
      for (int i = 0; i < 4; ++i)
        #pragma unroll
        for (int jq = 0; jq < 4; ++jq)
          acc[i][jq] = __builtin_amdgcn_mfma_f32_16x16x32_f16(a[i], bfr[jq], acc[i][jq], 0, 0, 0);
    }
  }

  #pragma unroll
  for (int i = 0; i < 4; ++i) {
    #pragma unroll
    for (int r = 0; r < 4; ++r) {
      unsigned mm = m0 + wm * 64 + i * 16 + ((lane >> 4) << 2) + r;
      unsigned bse = mm << 10;
      unsigned bsp = (mm - 64) << 10;
      #pragma unroll
      for (int jq = 0; jq < 4; ++jq) {
        int col2 = wn * 64 + jq * 16 + (lane & 15);
        float gx = uph(P[bse + 768 + col2]);
        float hnew = uph(P[bse + col2]);
        float hp = (mm >= 64) ? uph(P[bsp + col2]) : 0.f;
        float g = sigm(acc[i][jq][r] + gx);
        acc[i][jq][r] = g * hnew + (1.f - g) * hp;
      }
    }
  }
  #pragma unroll
  for (int i = 0; i < 4; ++i) {
    #pragma unroll
    for (int r = 0; r < 4; ++r) {
      float s1 = acc[i][0][r] + acc[i][1][r] + acc[i][2][r] + acc[i][3][r];
      float s2 = acc[i][0][r]*acc[i][0][r] + acc[i][1][r]*acc[i][1][r]
               + acc[i][2][r]*acc[i][2][r] + acc[i][3][r]*acc[i][3][r];
      s1 += __shfl_xor(s1, 1); s2 += __shfl_xor(s2, 1);
      s1 += __shfl_xor(s1, 2); s2 += __shfl_xor(s2, 2);
      s1 += __shfl_xor(s1, 4); s2 += __shfl_xor(s2, 4);
      s1 += __shfl_xor(s1, 8); s2 += __shfl_xor(s2, 8);
      if ((lane & 15) == 0) {
        int rowl = wm * 64 + i * 16 + ((lane >> 4) << 2) + r;
        red1[rowl][wn] = s1;
        red2[rowl][wn] = s2;
      }
    }
  }
  __syncthreads();
  if (t < 128) {
    float S1 = red1[t][0] + red1[t][1] + red1[t][2] + red1[t][3];
    float S2 = red2[t][0] + red2[t][1] + red2[t][2] + red2[t][3];
    float mu = S1 * (1.0f / 256.0f);
    float var = S2 * (1.0f / 256.0f) - mu * mu;
    murs[t] = make_float2(mu, rsqrtf(var + 1e-5f));
  }
  __syncthreads();
  #pragma unroll
  for (int i = 0; i < 4; ++i) {
    #pragma unroll
    for (int r = 0; r < 4; ++r) {
      int rowl = wm * 64 + i * 16 + ((lane >> 4) << 2) + r;
      float2 mr = murs[rowl];
      unsigned mm = m0 + rowl;
      #pragma unroll
      for (int jq = 0; jq < 4; ++jq) {
        int col2 = wn * 64 + jq * 16 + (lane & 15);
        out[(size_t)mm * 256 + col2] = (acc[i][jq][r] - mr.x) * mr.y * gam4[jq] + bet4[jq];
      }
    }
  }
}

extern "C" void kernel_launch(void* const* d_in, const int* in_sizes, int n_in,
                              void* d_out, int out_size, void* d_ws, size_t ws_size,
                              hipStream_t stream) {
  const float* x  = (const float*)d_in[0];
  const float* Wz = (const float*)d_in[1];
  const float* bz = (const float*)d_in[2];
  const float* Wr = (const float*)d_in[3];
  const float* br = (const float*)d_in[4];
  const float* Wc = (const float*)d_in[5];
  const float* bc = (const float*)d_in[6];
  const float* Wh = (const float*)d_in[7];
  const float* bh = (const float*)d_in[8];
  const float* gamma = (const float*)d_in[9];
  const float* beta  = (const float*)d_in[10];
  unsigned short* P = (unsigned short*)d_ws;   // 131072 x 1024 f16 = 256 MB
  float* out = (float*)d_out;

  dim3 g1(8, 1024);
  gemm_pre<<<g1, 256, 0, stream>>>(x, Wz, bz, Wr, br, Wc, bc, Wh, bh, P);
  gru_scan<<<64, 512, 0, stream>>>(Wz, Wr, Wc, P, out);
  g_mfma_ln<<<1024, 512, 0, stream>>>(Wh, gamma, beta, P, out);
}

// Round 15
// 2180.080 us; speedup vs baseline: 1.1689x; 1.1689x over previous
//
#include <hip/hip_runtime.h>

typedef _Float16 half2v __attribute__((ext_vector_type(2)));
typedef _Float16 half8v __attribute__((ext_vector_type(8)));
typedef float f32x4 __attribute__((ext_vector_type(4)));
typedef int i32x8 __attribute__((ext_vector_type(8)));

#define S_LEN 2048

// barrier draining only LDS counters (cross-wave traffic is all LDS here)
#define LDS_BARRIER() asm volatile("s_waitcnt lgkmcnt(0)\n\ts_barrier" ::: "memory")

static __device__ __forceinline__ unsigned int pk16(float a, float b) {
  half2v h; h[0] = (_Float16)a; h[1] = (_Float16)b;
  return __builtin_bit_cast(unsigned int, h);
}
static __device__ __forceinline__ float uph(unsigned short u) {
  return (float)__builtin_bit_cast(_Float16, u);
}
static __device__ __forceinline__ unsigned short f16bits(float x) {
  return __builtin_bit_cast(unsigned short, (_Float16)x);
}
static __device__ __forceinline__ float rcp_f(float x) {
  return __builtin_amdgcn_rcpf(x);
}
static __device__ __forceinline__ float sigm(float x) {
  return rcp_f(1.0f + __expf(-x));
}
static __device__ __forceinline__ float tanh_fast(float x) {
  return 1.0f - 2.0f * rcp_f(__expf(2.0f * x) + 1.0f);   // safe at +/-inf
}
static __device__ __forceinline__ float sel4(f32x4 v, int b) {
  return (b == 0) ? v[0] : (b == 1) ? v[1] : (b == 2) ? v[2] : v[3];
}
static __device__ __forceinline__ unsigned char fp8b(float x) {
  return (unsigned char)__builtin_amdgcn_cvt_pk_fp8_f32(x, x, 0, false);
}
// pack 32 consecutive f32 into 32 OCP-e4m3 bytes (one K=128 MFMA fragment)
static __device__ __forceinline__ i32x8 cvt32_fp8(const float* p) {
  i32x8 v;
  #pragma unroll
  for (int q = 0; q < 4; ++q) {
    int lo = 0, hi = 0;
    lo = __builtin_amdgcn_cvt_pk_fp8_f32(p[8*q+0], p[8*q+1], lo, false);
    lo = __builtin_amdgcn_cvt_pk_fp8_f32(p[8*q+2], p[8*q+3], lo, true);
    hi = __builtin_amdgcn_cvt_pk_fp8_f32(p[8*q+4], p[8*q+5], hi, false);
    hi = __builtin_amdgcn_cvt_pk_fp8_f32(p[8*q+6], p[8*q+7], hi, true);
    v[2*q] = lo; v[2*q+1] = hi;
  }
  return v;
}

// ---------------------------------------------------------------------------
// Kernel 1: P[m, g*256+j] = f16( x[m,:] . W{g}_x[j,:] + b{g}[j] )  (unchanged)
// ---------------------------------------------------------------------------
__global__ __launch_bounds__(256, 2) void gemm_pre(
    const float* __restrict__ x,
    const float* __restrict__ Wz, const float* __restrict__ bz,
    const float* __restrict__ Wr, const float* __restrict__ br,
    const float* __restrict__ Wc, const float* __restrict__ bc,
    const float* __restrict__ Wh, const float* __restrict__ bh,
    unsigned short* __restrict__ P)
{
  __shared__ __align__(16) char As[128 * 128];
  __shared__ __align__(16) char Bs[128 * 128];
  const int t = threadIdx.x;
  const int lane = t & 63;
  const int wid = t >> 6;
  const int wm = wid >> 1, wn = wid & 1;
  const int n0 = blockIdx.x * 128;
  const int m0 = blockIdx.y * 128;

  f32x4 acc[4][4];
  #pragma unroll
  for (int i = 0; i < 4; ++i)
    #pragma unroll
    for (int jq = 0; jq < 4; ++jq) acc[i][jq] = f32x4{0.f, 0.f, 0.f, 0.f};

  for (int kk = 0; kk < 4; ++kk) {
    __syncthreads();
    #pragma unroll
    for (int it = 0; it < 8; ++it) {
      int fl = it * 256 + t;
      int row = fl >> 4;
      int c4 = fl & 15;
      f32x4 v = *(const f32x4*)(x + (size_t)(m0 + row) * 256 + kk * 64 + c4 * 4);
      uint2 pw; pw.x = pk16(v[0], v[1]); pw.y = pk16(v[2], v[3]);
      *(uint2*)(As + row * 128 + ((c4 * 8) ^ ((row & 7) << 4))) = pw;

      int n = n0 + row;
      int g = n >> 8; int jc = n & 255;
      const float* W = (g == 0) ? Wz : (g == 1) ? Wr : (g == 2) ? Wc : Wh;
      f32x4 wv = *(const f32x4*)(W + jc * 512 + kk * 64 + c4 * 4);
      uint2 qw; qw.x = pk16(wv[0], wv[1]); qw.y = pk16(wv[2], wv[3]);
      *(uint2*)(Bs + row * 128 + ((c4 * 8) ^ ((row & 7) << 4))) = qw;
    }
    __syncthreads();
    #pragma unroll
    for (int k2 = 0; k2 < 2; ++k2) {
      const int kb = k2 * 64 + (lane >> 4) * 16;
      half8v a[4], bfr[4];
      #pragma unroll
      for (int i = 0; i < 4; ++i) {
        int ar = wm * 64 + i * 16 + (lane & 15);
        a[i] = *(const half8v*)(As + ar * 128 + (kb ^ ((ar & 7) << 4)));
        int br2 = wn * 64 + i * 16 + (lane & 15);
        bfr[i] = *(const half8v*)(Bs + br2 * 128 + (kb ^ ((br2 & 7) << 4)));
      }
      #pragma unroll
      for (int i = 0; i < 4; ++i)
        #pragma unroll
        for (int jq = 0; jq < 4; ++jq)
          acc[i][jq] = __builtin_amdgcn_mfma_f32_16x16x32_f16(a[i], bfr[jq], acc[i][jq], 0, 0, 0);
    }
  }
  #pragma unroll
  for (int jq = 0; jq < 4; ++jq) {
    int col = n0 + wn * 64 + jq * 16 + (lane & 15);
    int g = col >> 8; int jc = col & 255;
    const float* bp = (g == 0) ? bz : (g == 1) ? br : (g == 2) ? bc : bh;
    float bias = bp[jc];
    #pragma unroll
    for (int i = 0; i < 4; ++i) {
      int rowb = m0 + wm * 64 + i * 16 + (lane >> 4) * 4;
      #pragma unroll
      for (int r = 0; r < 4; ++r) {
        float vv = acc[i][jq][r] + bias;
        P[(size_t)(rowb + r) * 1024 + col] = f16bits(vv);
      }
    }
  }
}

// ---------------------------------------------------------------------------
// Kernel 2: sequential scan. 64 blocks x 1024 threads (16 waves, 4/SIMD —
// R13 config, best overlap point). Wave w owns rows [w*16,+16) of z, r, c.
// All matvecs MX fp8 K=128 (unit scales). r-MFMAs issue FIRST (r->rh is the
// pre-barrier critical chain); z-gate sigmoid deferred into phase C's MFMA
// shadow. h and rh published as fp8.
// ---------------------------------------------------------------------------
__global__ __launch_bounds__(1024, 1) void gru_scan(
    const float* __restrict__ Wz, const float* __restrict__ Wr,
    const float* __restrict__ Wc,
    unsigned short* P, float* __restrict__ out)
{
  __shared__ __align__(16) unsigned char h8_lds[256];   // h as fp8 e4m3
  __shared__ __align__(16) unsigned char rh8_lds[256];  // r*h as fp8 e4m3

  const int t = threadIdx.x;
  const int b = blockIdx.x;
  const int w = t >> 6;            // 0..15
  const int l = t & 63;
  const int col = l & 15;
  const int khi = l >> 4;          // 0..3
  const int lb = l & 3;
  const bool owner = (col < 4);    // then lb == col
  const int j0 = w * 16 + khi * 4 + lb;

  // ---- A-frags (K=128 scaled): lane (khi,col) holds
  //      W[row=w*16+col][k = half*128 + khi*32 + e], e=0..31
  i32x8 wzMX[2], wrMX[2], wcMX[2];
  {
    int row = w * 16 + col;
    #pragma unroll
    for (int hf = 0; hf < 2; ++hf) {
      wzMX[hf] = cvt32_fp8(Wz + row * 512 + 256 + hf * 128 + khi * 32);
      wrMX[hf] = cvt32_fp8(Wr + row * 512 + 256 + hf * 128 + khi * 32);
      wcMX[hf] = cvt32_fp8(Wc + row * 512 + 256 + hf * 128 + khi * 32);
    }
  }

  if (t < 64) ((unsigned int*)h8_lds)[t] = 0u;

  float h0 = 0.f;
  unsigned short czx = 0, crx = 0, ccx = 0;
  if (owner) {
    const unsigned short* pb = P + b * 1024;
    czx = pb[j0]; crx = pb[256 + j0]; ccx = pb[512 + j0];
  }
  int pcur = b * 1024;
  int pnext = pcur + 65536;
  __syncthreads();

  const f32x4 z4 = f32x4{0.f, 0.f, 0.f, 0.f};

  #pragma unroll 1
  for (int s = 0; s < S_LEN; ++s) {
    unsigned short nzx = 0, nrx = 0, ncx = 0;
    if (owner && s + 1 < S_LEN) {
      nzx = P[pnext + j0];
      nrx = P[pnext + 256 + j0];
      ncx = P[pnext + 512 + j0];
    }
    // ---- Phase A: r first (critical chain into barrier 1), then z
    i32x8 hB0 = *(const i32x8*)(h8_lds + khi * 32);
    i32x8 hB1 = *(const i32x8*)(h8_lds + 128 + khi * 32);
    f32x4 ar = z4, az = z4;
    ar = __builtin_amdgcn_mfma_scale_f32_16x16x128_f8f6f4(
             wrMX[0], hB0, ar, 0, 0, 0, 0x7F7F7F7F, 0, 0x7F7F7F7F);
    ar = __builtin_amdgcn_mfma_scale_f32_16x16x128_f8f6f4(
             wrMX[1], hB1, ar, 0, 0, 0, 0x7F7F7F7F, 0, 0x7F7F7F7F);
    az = __builtin_amdgcn_mfma_scale_f32_16x16x128_f8f6f4(
             wzMX[0], hB0, az, 0, 0, 0, 0x7F7F7F7F, 0, 0x7F7F7F7F);
    az = __builtin_amdgcn_mfma_scale_f32_16x16x128_f8f6f4(
             wzMX[1], hB1, az, 0, 0, 0, 0x7F7F7F7F, 0, 0x7F7F7F7F);
    {
      float r0 = sigm(sel4(ar, lb) + uph(crx));
      if (owner) rh8_lds[j0] = fp8b(r0 * h0);
    }
    LDS_BARRIER();                                     // (1) rh ready
    // ---- Phase C: c matvec; z-gate + tanh math in the MFMA shadow
    i32x8 rB0 = *(const i32x8*)(rh8_lds + khi * 32);
    i32x8 rB1 = *(const i32x8*)(rh8_lds + 128 + khi * 32);
    f32x4 ac = z4;
    ac = __builtin_amdgcn_mfma_scale_f32_16x16x128_f8f6f4(
             wcMX[0], rB0, ac, 0, 0, 0, 0x7F7F7F7F, 0, 0x7F7F7F7F);
    ac = __builtin_amdgcn_mfma_scale_f32_16x16x128_f8f6f4(
             wcMX[1], rB1, ac, 0, 0, 0, 0x7F7F7F7F, 0, 0x7F7F7F7F);
    float zg = sigm(sel4(az, lb) + uph(czx));          // deferred z-gate
    float ht = tanh_fast(sel4(ac, lb) + uph(ccx));
    float hn = (1.f - zg) * h0 + zg * ht;
    h0 = hn;
    if (owner) {
      h8_lds[j0] = fp8b(hn);
      P[pcur + j0] = f16bits(hn);
    }
    czx = nzx; crx = nrx; ccx = ncx;
    pcur += 65536; pnext += 65536;
    LDS_BARRIER();                                     // (2) h ready
  }
  if (owner) out[(size_t)33554432 + b * 256 + j0] = h0;
}

// ---------------------------------------------------------------------------
// Kernel 3: g-gate + highway + LayerNorm as MFMA GEMM. (unchanged)
// ---------------------------------------------------------------------------
__global__ __launch_bounds__(512, 2) void g_mfma_ln(
    const float* __restrict__ Wh,
    const float* __restrict__ gamma, const float* __restrict__ beta,
    const unsigned short* __restrict__ P,
    float* __restrict__ out)
{
  __shared__ __align__(16) char As[128 * 128];    // hprev tile f16 (swizzled)
  __shared__ __align__(16) char Bs[256 * 128];    // Wg tile f16 (swizzled)
  __shared__ float red1[128][4];
  __shared__ float red2[128][4];
  __shared__ float2 murs[128];

  const int t = threadIdx.x;
  const int lane = t & 63;
  const int wid = t >> 6;
  const int wm = wid >> 2, wn = wid & 3;          // 2 x 4 wave grid
  const unsigned m0 = blockIdx.x * 128;

  float gam4[4], bet4[4];
  #pragma unroll
  for (int jq = 0; jq < 4; ++jq) {
    int col = wn * 64 + jq * 16 + (lane & 15);
    gam4[jq] = gamma[col];
    bet4[jq] = beta[col];
  }

  f32x4 acc[4][4];
  #pragma unroll
  for (int i = 0; i < 4; ++i)
    #pragma unroll
    for (int jq = 0; jq < 4; ++jq) acc[i][jq] = f32x4{0.f, 0.f, 0.f, 0.f};

  for (int kk = 0; kk < 4; ++kk) {
    __syncthreads();
    #pragma unroll
    for (int it = 0; it < 2; ++it) {
      int g = it * 512 + t;
      int row = g >> 3;
      int c8 = g & 7;
      int msrc = (int)m0 + row - 64;
      uint4 v = uint4{0u, 0u, 0u, 0u};
      if (msrc >= 0) v = *(const uint4*)(P + (unsigned)msrc * 1024 + kk * 64 + c8 * 8);
      *(uint4*)(As + row * 128 + ((c8 * 16) ^ ((row & 7) << 4))) = v;
    }
    #pragma unroll
    for (int it = 0; it < 4; ++it) {
      int g = it * 512 + t;
      int row = g >> 3;
      int c8 = g & 7;
      const float* src = Wh + row * 512 + 256 + kk * 64 + c8 * 8;
      f32x4 v0 = *(const f32x4*)(src);
      f32x4 v1 = *(const f32x4*)(src + 4);
      uint4 pw;
      pw.x = pk16(v0[0], v0[1]); pw.y = pk16(v0[2], v0[3]);
      pw.z = pk16(v1[0], v1[1]); pw.w = pk16(v1[2], v1[3]);
      *(uint4*)(Bs + row * 128 + ((c8 * 16) ^ ((row & 7) << 4))) = pw;
    }
    __syncthreads();
    #pragma unroll
    for (int k2 = 0; k2 < 2; ++k2) {
      const int kb = k2 * 64 + (lane >> 4) * 16;
      half8v a[4], bfr[4];
      #pragma unroll
      for (int i = 0; i < 4; ++i) {
        int ar = wm * 64 + i * 16 + (lane & 15);
        a[i] = *(const half8v*)(As + ar * 128 + (kb ^ ((ar & 7) << 4)));
        int br2 = wn * 64 + i * 16 + (lane & 15);
        bfr[i] = *(const half8v*)(Bs + br2 * 128 + (kb ^ ((br2 & 7) << 4)));
      }
      #pragma unroll
      for (int i = 0; i < 4; ++i)
        #pragma unroll
        for (int jq = 0; jq < 4; ++jq)
          acc[i][jq] = __builtin_amdgcn_mfma_f32_16x16x32_f16(a[i], bfr[jq], acc[i][jq], 0, 0, 0);
    }
  }

  #pragma unroll
  for (int i = 0; i < 4; ++i) {
    #pragma unroll
    for (int r = 0; r < 4; ++r) {
      unsigned mm = m0 + wm * 64 + i * 16 + ((lane >> 4) << 2) + r;
      unsigned bse = mm << 10;
      unsigned bsp = (mm - 64) << 10;
      #pragma unroll
      for (int jq = 0; jq < 4; ++jq) {
        int col2 = wn * 64 + jq * 16 + (lane & 15);
        float gx = uph(P[bse + 768 + col2]);
        float hnew = uph(P[bse + col2]);
        float hp = (mm >= 64) ? uph(P[bsp + col2]) : 0.f;
        float g = sigm(acc[i][jq][r] + gx);
        acc[i][jq][r] = g * hnew + (1.f - g) * hp;
      }
    }
  }
  #pragma unroll
  for (int i = 0; i < 4; ++i) {
    #pragma unroll
    for (int r = 0; r < 4; ++r) {
      float s1 = acc[i][0][r] + acc[i][1][r] + acc[i][2][r] + acc[i][3][r];
      float s2 = acc[i][0][r]*acc[i][0][r] + acc[i][1][r]*acc[i][1][r]
               + acc[i][2][r]*acc[i][2][r] + acc[i][3][r]*acc[i][3][r];
      s1 += __shfl_xor(s1, 1); s2 += __shfl_xor(s2, 1);
      s1 += __shfl_xor(s1, 2); s2 += __shfl_xor(s2, 2);
      s1 += __shfl_xor(s1, 4); s2 += __shfl_xor(s2, 4);
      s1 += __shfl_xor(s1, 8); s2 += __shfl_xor(s2, 8);
      if ((lane & 15) == 0) {
        int rowl = wm * 64 + i * 16 + ((lane >> 4) << 2) + r;
        red1[rowl][wn] = s1;
        red2[rowl][wn] = s2;
      }
    }
  }
  __syncthreads();
  if (t < 128) {
    float S1 = red1[t][0] + red1[t][1] + red1[t][2] + red1[t][3];
    float S2 = red2[t][0] + red2[t][1] + red2[t][2] + red2[t][3];
    float mu = S1 * (1.0f / 256.0f);
    float var = S2 * (1.0f / 256.0f) - mu * mu;
    murs[t] = make_float2(mu, rsqrtf(var + 1e-5f));
  }
  __syncthreads();
  #pragma unroll
  for (int i = 0; i < 4; ++i) {
    #pragma unroll
    for (int r = 0; r < 4; ++r) {
      int rowl = wm * 64 + i * 16 + ((lane >> 4) << 2) + r;
      float2 mr = murs[rowl];
      unsigned mm = m0 + rowl;
      #pragma unroll
      for (int jq = 0; jq < 4; ++jq) {
        int col2 = wn * 64 + jq * 16 + (lane & 15);
        out[(size_t)mm * 256 + col2] = (acc[i][jq][r] - mr.x) * mr.y * gam4[jq] + bet4[jq];
      }
    }
  }
}

extern "C" void kernel_launch(void* const* d_in, const int* in_sizes, int n_in,
                              void* d_out, int out_size, void* d_ws, size_t ws_size,
                              hipStream_t stream) {
  const float* x  = (const float*)d_in[0];
  const float* Wz = (const float*)d_in[1];
  const float* bz = (const float*)d_in[2];
  const float* Wr = (const float*)d_in[3];
  const float* br = (const float*)d_in[4];
  const float* Wc = (const float*)d_in[5];
  const float* bc = (const float*)d_in[6];
  const float* Wh = (const float*)d_in[7];
  const float* bh = (const float*)d_in[8];
  const float* gamma = (const float*)d_in[9];
  const float* beta  = (const float*)d_in[10];
  unsigned short* P = (unsigned short*)d_ws;   // 131072 x 1024 f16 = 256 MB
  float* out = (float*)d_out;

  dim3 g1(8, 1024);
  gemm_pre<<<g1, 256, 0, stream>>>(x, Wz, bz, Wr, br, Wc, bc, Wh, bh, P);
  gru_scan<<<64, 1024, 0, stream>>>(Wz, Wr, Wc, P, out);
  g_mfma_ln<<<1024, 512, 0, stream>>>(Wh, gamma, beta, P, out);
}

// Round 16
// 2173.668 us; speedup vs baseline: 1.1723x; 1.0029x over previous
//
#include <hip/hip_runtime.h>

typedef _Float16 half2v __attribute__((ext_vector_type(2)));
typedef _Float16 half8v __attribute__((ext_vector_type(8)));
typedef float f32x4 __attribute__((ext_vector_type(4)));
typedef int i32x8 __attribute__((ext_vector_type(8)));

#define S_LEN 2048

// barrier draining only LDS counters (cross-wave traffic is all LDS here)
#define LDS_BARRIER() asm volatile("s_waitcnt lgkmcnt(0)\n\ts_barrier" ::: "memory")

static __device__ __forceinline__ unsigned int pk16(float a, float b) {
  half2v h; h[0] = (_Float16)a; h[1] = (_Float16)b;
  return __builtin_bit_cast(unsigned int, h);
}
static __device__ __forceinline__ float uph(unsigned short u) {
  return (float)__builtin_bit_cast(_Float16, u);
}
static __device__ __forceinline__ unsigned short f16bits(float x) {
  return __builtin_bit_cast(unsigned short, (_Float16)x);
}
static __device__ __forceinline__ float rcp_f(float x) {
  return __builtin_amdgcn_rcpf(x);
}
static __device__ __forceinline__ float sigm(float x) {
  return rcp_f(1.0f + __expf(-x));
}
static __device__ __forceinline__ float tanh_fast(float x) {
  return 1.0f - 2.0f * rcp_f(__expf(2.0f * x) + 1.0f);   // safe at +/-inf
}
static __device__ __forceinline__ float sel4(f32x4 v, int b) {
  return (b == 0) ? v[0] : (b == 1) ? v[1] : (b == 2) ? v[2] : v[3];
}
static __device__ __forceinline__ unsigned char fp8b(float x) {
  return (unsigned char)__builtin_amdgcn_cvt_pk_fp8_f32(x, x, 0, false);
}
// pack 32 consecutive f32 into 32 OCP-e4m3 bytes (one K=128 MFMA fragment)
static __device__ __forceinline__ i32x8 cvt32_fp8(const float* p) {
  i32x8 v;
  #pragma unroll
  for (int q = 0; q < 4; ++q) {
    int lo = 0, hi = 0;
    lo = __builtin_amdgcn_cvt_pk_fp8_f32(p[8*q+0], p[8*q+1], lo, false);
    lo = __builtin_amdgcn_cvt_pk_fp8_f32(p[8*q+2], p[8*q+3], lo, true);
    hi = __builtin_amdgcn_cvt_pk_fp8_f32(p[8*q+4], p[8*q+5], hi, false);
    hi = __builtin_amdgcn_cvt_pk_fp8_f32(p[8*q+6], p[8*q+7], hi, true);
    v[2*q] = lo; v[2*q+1] = hi;
  }
  return v;
}

// ---------------------------------------------------------------------------
// Kernel 1: P[m, g*256+j] = f16( x[m,:] . W{g}_x[j,:] + b{g}[j] )  (unchanged)
// ---------------------------------------------------------------------------
__global__ __launch_bounds__(256, 2) void gemm_pre(
    const float* __restrict__ x,
    const float* __restrict__ Wz, const float* __restrict__ bz,
    const float* __restrict__ Wr, const float* __restrict__ br,
    const float* __restrict__ Wc, const float* __restrict__ bc,
    const float* __restrict__ Wh, const float* __restrict__ bh,
    unsigned short* __restrict__ P)
{
  __shared__ __align__(16) char As[128 * 128];
  __shared__ __align__(16) char Bs[128 * 128];
  const int t = threadIdx.x;
  const int lane = t & 63;
  const int wid = t >> 6;
  const int wm = wid >> 1, wn = wid & 1;
  const int n0 = blockIdx.x * 128;
  const int m0 = blockIdx.y * 128;

  f32x4 acc[4][4];
  #pragma unroll
  for (int i = 0; i < 4; ++i)
    #pragma unroll
    for (int jq = 0; jq < 4; ++jq) acc[i][jq] = f32x4{0.f, 0.f, 0.f, 0.f};

  for (int kk = 0; kk < 4; ++kk) {
    __syncthreads();
    #pragma unroll
    for (int it = 0; it < 8; ++it) {
      int fl = it * 256 + t;
      int row = fl >> 4;
      int c4 = fl & 15;
      f32x4 v = *(const f32x4*)(x + (size_t)(m0 + row) * 256 + kk * 64 + c4 * 4);
      uint2 pw; pw.x = pk16(v[0], v[1]); pw.y = pk16(v[2], v[3]);
      *(uint2*)(As + row * 128 + ((c4 * 8) ^ ((row & 7) << 4))) = pw;

      int n = n0 + row;
      int g = n >> 8; int jc = n & 255;
      const float* W = (g == 0) ? Wz : (g == 1) ? Wr : (g == 2) ? Wc : Wh;
      f32x4 wv = *(const f32x4*)(W + jc * 512 + kk * 64 + c4 * 4);
      uint2 qw; qw.x = pk16(wv[0], wv[1]); qw.y = pk16(wv[2], wv[3]);
      *(uint2*)(Bs + row * 128 + ((c4 * 8) ^ ((row & 7) << 4))) = qw;
    }
    __syncthreads();
    #pragma unroll
    for (int k2 = 0; k2 < 2; ++k2) {
      const int kb = k2 * 64 + (lane >> 4) * 16;
      half8v a[4], bfr[4];
      #pragma unroll
      for (int i = 0; i < 4; ++i) {
        int ar = wm * 64 + i * 16 + (lane & 15);
        a[i] = *(const half8v*)(As + ar * 128 + (kb ^ ((ar & 7) << 4)));
        int br2 = wn * 64 + i * 16 + (lane & 15);
        bfr[i] = *(const half8v*)(Bs + br2 * 128 + (kb ^ ((br2 & 7) << 4)));
      }
      #pragma unroll
      for (int i = 0; i < 4; ++i)
        #pragma unroll
        for (int jq = 0; jq < 4; ++jq)
          acc[i][jq] = __builtin_amdgcn_mfma_f32_16x16x32_f16(a[i], bfr[jq], acc[i][jq], 0, 0, 0);
    }
  }
  #pragma unroll
  for (int jq = 0; jq < 4; ++jq) {
    int col = n0 + wn * 64 + jq * 16 + (lane & 15);
    int g = col >> 8; int jc = col & 255;
    const float* bp = (g == 0) ? bz : (g == 1) ? br : (g == 2) ? bc : bh;
    float bias = bp[jc];
    #pragma unroll
    for (int i = 0; i < 4; ++i) {
      int rowb = m0 + wm * 64 + i * 16 + (lane >> 4) * 4;
      #pragma unroll
      for (int r = 0; r < 4; ++r) {
        float vv = acc[i][jq][r] + bias;
        P[(size_t)(rowb + r) * 1024 + col] = f16bits(vv);
      }
    }
  }
}

// ---------------------------------------------------------------------------
// Kernel 2: sequential scan. 64 blocks x 1024 threads (16 waves, 4/SIMD).
// Wave w owns rows [w*16,+16) of z, r, c; all matvecs MX fp8 K=128 (unit
// scales). h8 double-buffered: phase A holds hB in regs, z-MFMAs moved to
// phase C (reuse hB, new h goes to the other buffer). Branchless prefetch.
// ---------------------------------------------------------------------------
__global__ __launch_bounds__(1024, 1) void gru_scan(
    const float* __restrict__ Wz, const float* __restrict__ Wr,
    const float* __restrict__ Wc,
    unsigned short* P, float* __restrict__ out)
{
  __shared__ __align__(16) unsigned char h8_lds[2][256];  // h fp8, double-buffered
  __shared__ __align__(16) unsigned char rh8_lds[256];    // r*h fp8

  const int t = threadIdx.x;
  const int b = blockIdx.x;
  const int w = t >> 6;            // 0..15
  const int l = t & 63;
  const int col = l & 15;
  const int khi = l >> 4;          // 0..3
  const int lb = l & 3;
  const bool owner = (col < 4);    // then lb == col
  const int j0 = w * 16 + khi * 4 + lb;

  // ---- A-frags (K=128 scaled): lane (khi,col) holds
  //      W[row=w*16+col][k = half*128 + khi*32 + e], e=0..31
  i32x8 wzMX[2], wrMX[2], wcMX[2];
  {
    int row = w * 16 + col;
    #pragma unroll
    for (int hf = 0; hf < 2; ++hf) {
      wzMX[hf] = cvt32_fp8(Wz + row * 512 + 256 + hf * 128 + khi * 32);
      wrMX[hf] = cvt32_fp8(Wr + row * 512 + 256 + hf * 128 + khi * 32);
      wcMX[hf] = cvt32_fp8(Wc + row * 512 + 256 + hf * 128 + khi * 32);
    }
  }

  if (t < 64) { ((unsigned int*)h8_lds[0])[t] = 0u; }

  float h0 = 0.f;
  unsigned short czx = 0, crx = 0, ccx = 0;
  if (owner) {
    const unsigned short* pb = P + b * 1024;
    czx = pb[j0]; crx = pb[256 + j0]; ccx = pb[512 + j0];
  }
  int pcur = b * 1024;
  const int plast = b * 1024 + (S_LEN - 1) * 65536;
  __syncthreads();

  const f32x4 z4 = f32x4{0.f, 0.f, 0.f, 0.f};

  #pragma unroll 1
  for (int s = 0; s < S_LEN; ++s) {
    const unsigned char* hcur = h8_lds[s & 1];
    unsigned char* hnxt = h8_lds[(s + 1) & 1];
    // branchless prefetch: clamped address; final-step values simply unused
    int pnext = (pcur + 65536 <= plast) ? (pcur + 65536) : plast;
    unsigned short nzx = 0, nrx = 0, ncx = 0;
    if (owner) {
      nzx = P[pnext + j0];
      nrx = P[pnext + 256 + j0];
      ncx = P[pnext + 512 + j0];
    }
    // ---- Phase A: pure r-chain into barrier (1)
    i32x8 hB0 = *(const i32x8*)(hcur + khi * 32);
    i32x8 hB1 = *(const i32x8*)(hcur + 128 + khi * 32);
    f32x4 ar = z4;
    ar = __builtin_amdgcn_mfma_scale_f32_16x16x128_f8f6f4(
             wrMX[0], hB0, ar, 0, 0, 0, 0x7F7F7F7F, 0, 0x7F7F7F7F);
    ar = __builtin_amdgcn_mfma_scale_f32_16x16x128_f8f6f4(
             wrMX[1], hB1, ar, 0, 0, 0, 0x7F7F7F7F, 0, 0x7F7F7F7F);
    {
      float r0 = sigm(sel4(ar, lb) + uph(crx));
      if (owner) rh8_lds[j0] = fp8b(r0 * h0);
    }
    LDS_BARRIER();                                     // (1) rh ready
    // ---- Phase C: z (reusing hB regs) + c matvecs; gate math in shadow
    f32x4 az = z4, ac = z4;
    az = __builtin_amdgcn_mfma_scale_f32_16x16x128_f8f6f4(
             wzMX[0], hB0, az, 0, 0, 0, 0x7F7F7F7F, 0, 0x7F7F7F7F);
    az = __builtin_amdgcn_mfma_scale_f32_16x16x128_f8f6f4(
             wzMX[1], hB1, az, 0, 0, 0, 0x7F7F7F7F, 0, 0x7F7F7F7F);
    i32x8 rB0 = *(const i32x8*)(rh8_lds + khi * 32);
    i32x8 rB1 = *(const i32x8*)(rh8_lds + 128 + khi * 32);
    ac = __builtin_amdgcn_mfma_scale_f32_16x16x128_f8f6f4(
             wcMX[0], rB0, ac, 0, 0, 0, 0x7F7F7F7F, 0, 0x7F7F7F7F);
    ac = __builtin_amdgcn_mfma_scale_f32_16x16x128_f8f6f4(
             wcMX[1], rB1, ac, 0, 0, 0, 0x7F7F7F7F, 0, 0x7F7F7F7F);
    float zg = sigm(sel4(az, lb) + uph(czx));
    float ht = tanh_fast(sel4(ac, lb) + uph(ccx));
    float hn = h0 + zg * (ht - h0);
    h0 = hn;
    if (owner) {
      hnxt[j0] = fp8b(hn);
      P[pcur + j0] = f16bits(hn);
    }
    czx = nzx; crx = nrx; ccx = ncx;
    pcur = pnext;
    LDS_BARRIER();                                     // (2) h ready
  }
  if (owner) out[(size_t)33554432 + b * 256 + j0] = h0;
}

// ---------------------------------------------------------------------------
// Kernel 3: g-gate + highway + LayerNorm as MFMA GEMM. (unchanged)
// ---------------------------------------------------------------------------
__global__ __launch_bounds__(512, 2) void g_mfma_ln(
    const float* __restrict__ Wh,
    const float* __restrict__ gamma, const float* __restrict__ beta,
    const unsigned short* __restrict__ P,
    float* __restrict__ out)
{
  __shared__ __align__(16) char As[128 * 128];    // hprev tile f16 (swizzled)
  __shared__ __align__(16) char Bs[256 * 128];    // Wg tile f16 (swizzled)
  __shared__ float red1[128][4];
  __shared__ float red2[128][4];
  __shared__ float2 murs[128];

  const int t = threadIdx.x;
  const int lane = t & 63;
  const int wid = t >> 6;
  const int wm = wid >> 2, wn = wid & 3;          // 2 x 4 wave grid
  const unsigned m0 = blockIdx.x * 128;

  float gam4[4], bet4[4];
  #pragma unroll
  for (int jq = 0; jq < 4; ++jq) {
    int col = wn * 64 + jq * 16 + (lane & 15);
    gam4[jq] = gamma[col];
    bet4[jq] = beta[col];
  }

  f32x4 acc[4][4];
  #pragma unroll
  for (int i = 0; i < 4; ++i)
    #pragma unroll
    for (int jq = 0; jq < 4; ++jq) acc[i][jq] = f32x4{0.f, 0.f, 0.f, 0.f};

  for (int kk = 0; kk < 4; ++kk) {
    __syncthreads();
    #pragma unroll
    for (int it = 0; it < 2; ++it) {
      int g = it * 512 + t;
      int row = g >> 3;
      int c8 = g & 7;
      int msrc = (int)m0 + row - 64;
      uint4 v = uint4{0u, 0u, 0u, 0u};
      if (msrc >= 0) v = *(const uint4*)(P + (unsigned)msrc * 1024 + kk * 64 + c8 * 8);
      *(uint4*)(As + row * 128 + ((c8 * 16) ^ ((row & 7) << 4))) = v;
    }
    #pragma unroll
    for (int it = 0; it < 4; ++it) {
      int g = it * 512 + t;
      int row = g >> 3;
      int c8 = g & 7;
      const float* src = Wh + row * 512 + 256 + kk * 64 + c8 * 8;
      f32x4 v0 = *(const f32x4*)(src);
      f32x4 v1 = *(const f32x4*)(src + 4);
      uint4 pw;
      pw.x = pk16(v0[0], v0[1]); pw.y = pk16(v0[2], v0[3]);
      pw.z = pk16(v1[0], v1[1]); pw.w = pk16(v1[2], v1[3]);
      *(uint4*)(Bs + row * 128 + ((c8 * 16) ^ ((row & 7) << 4))) = pw;
    }
    __syncthreads();
    #pragma unroll
    for (int k2 = 0; k2 < 2; ++k2) {
      const int kb = k2 * 64 + (lane >> 4) * 16;
      half8v a[4], bfr[4];
      #pragma unroll
      for (int i = 0; i < 4; ++i) {
        int ar = wm * 64 + i * 16 + (lane & 15);
        a[i] = *(const half8v*)(As + ar * 128 + (kb ^ ((ar & 7) << 4)));
        int br2 = wn * 64 + i * 16 + (lane & 15);
        bfr[i] = *(const half8v*)(Bs + br2 * 128 + (kb ^ ((br2 & 7) << 4)));
      }
      #pragma unroll
      for (int i = 0; i < 4; ++i)
        #pragma unroll
        for (int jq = 0; jq < 4; ++jq)
          acc[i][jq] = __builtin_amdgcn_mfma_f32_16x16x32_f16(a[i], bfr[jq], acc[i][jq], 0, 0, 0);
    }
  }

  #pragma unroll
  for (int i = 0; i < 4; ++i) {
    #pragma unroll
    for (int r = 0; r < 4; ++r) {
      unsigned mm = m0 + wm * 64 + i * 16 + ((lane >> 4) << 2) + r;
      unsigned bse = mm << 10;
      unsigned bsp = (mm - 64) << 10;
      #pragma unroll
      for (int jq = 0; jq < 4; ++jq) {
        int col2 = wn * 64 + jq * 16 + (lane & 15);
        float gx = uph(P[bse + 768 + col2]);
        float hnew = uph(P[bse + col2]);
        float hp = (mm >= 64) ? uph(P[bsp + col2]) : 0.f;
        float g = sigm(acc[i][jq][r] + gx);
        acc[i][jq][r] = g * hnew + (1.f - g) * hp;
      }
    }
  }
  #pragma unroll
  for (int i = 0; i < 4; ++i) {
    #pragma unroll
    for (int r = 0; r < 4; ++r) {
      float s1 = acc[i][0][r] + acc[i][1][r] + acc[i][2][r] + acc[i][3][r];
      float s2 = acc[i][0][r]*acc[i][0][r] + acc[i][1][r]*acc[i][1][r]
               + acc[i][2][r]*acc[i][2][r] + acc[i][3][r]*acc[i][3][r];
      s1 += __shfl_xor(s1, 1); s2 += __shfl_xor(s2, 1);
      s1 += __shfl_xor(s1, 2); s2 += __shfl_xor(s2, 2);
      s1 += __shfl_xor(s1, 4); s2 += __shfl_xor(s2, 4);
      s1 += __shfl_xor(s1, 8); s2 += __shfl_xor(s2, 8);
      if ((lane & 15) == 0) {
        int rowl = wm * 64 + i * 16 + ((lane >> 4) << 2) + r;
        red1[rowl][wn] = s1;
        red2[rowl][wn] = s2;
      }
    }
  }
  __syncthreads();
  if (t < 128) {
    float S1 = red1[t][0] + red1[t][1] + red1[t][2] + red1[t][3];
    float S2 = red2[t][0] + red2[t][1] + red2[t][2] + red2[t][3];
    float mu = S1 * (1.0f / 256.0f);
    float var = S2 * (1.0f / 256.0f) - mu * mu;
    murs[t] = make_float2(mu, rsqrtf(var + 1e-5f));
  }
  __syncthreads();
  #pragma unroll
  for (int i = 0; i < 4; ++i) {
    #pragma unroll
    for (int r = 0; r < 4; ++r) {
      int rowl = wm * 64 + i * 16 + ((lane >> 4) << 2) + r;
      float2 mr = murs[rowl];
      unsigned mm = m0 + rowl;
      #pragma unroll
      for (int jq = 0; jq < 4; ++jq) {
        int col2 = wn * 64 + jq * 16 + (lane & 15);
        out[(size_t)mm * 256 + col2] = (acc[i][jq][r] - mr.x) * mr.y * gam4[jq] + bet4[jq];
      }
    }
  }
}

extern "C" void kernel_launch(void* const* d_in, const int* in_sizes, int n_in,
                              void* d_out, int out_size, void* d_ws, size_t ws_size,
                              hipStream_t stream) {
  const float* x  = (const float*)d_in[0];
  const float* Wz = (const float*)d_in[1];
  const float* bz = (const float*)d_in[2];
  const float* Wr = (const float*)d_in[3];
  const float* br = (const float*)d_in[4];
  const float* Wc = (const float*)d_in[5];
  const float* bc = (const float*)d_in[6];
  const float* Wh = (const float*)d_in[7];
  const float* bh = (const float*)d_in[8];
  const float* gamma = (const float*)d_in[9];
  const float* beta  = (const float*)d_in[10];
  unsigned short* P = (unsigned short*)d_ws;   // 131072 x 1024 f16 = 256 MB
  float* out = (float*)d_out;

  dim3 g1(8, 1024);
  gemm_pre<<<g1, 256, 0, stream>>>(x, Wz, bz, Wr, br, Wc, bc, Wh, bh, P);
  gru_scan<<<64, 1024, 0, stream>>>(Wz, Wr, Wc, P, out);
  g_mfma_ln<<<1024, 512, 0, stream>>>(Wh, gamma, beta, P, out);
}